// Round 1
// 358.700 us; speedup vs baseline: 1.7681x; 1.7681x over previous
//
#include <hip/hip_runtime.h>
#include <math.h>

// Problem constants
#define BN 131072
#define KN 1024
#define DN 128
#define ROWS 128              // z rows per block
#define NBLK (BN / ROWS)      // 1024 blocks
#define GCODES 64             // codes per staged group
#define NGRP (KN / GCODES)    // 16 groups

// Ambiguity threshold on approx scores (esq - 2*dot).
// Sound if T > 2*delta_split + 2*(2*ulp(d2max~256)) ~= 1.66e-4 (see analysis).
#define TAMB 2.5e-4f
// Canary: |(zsq + best_score) - exact_d2(winner)| beyond this => gross error
// (e.g. wrong MFMA layout) -> force full exact rescan for the row.
#define CANARY 0.01f

typedef __attribute__((ext_vector_type(8))) short s16x8;   // 8 bf16 (4 VGPR)
typedef __attribute__((ext_vector_type(4))) short s16x4;   // 4 bf16 (8B)
typedef __attribute__((ext_vector_type(4))) float f32x4;   // MFMA C/D

__device__ __forceinline__ unsigned short f2bf(float f) {
    // round-to-nearest-even bf16 (finite inputs only)
    const unsigned int u = __float_as_uint(f);
    return (unsigned short)((u + 0x7fffu + ((u >> 16) & 1u)) >> 16);
}
__device__ __forceinline__ float bf2f(unsigned short s) {
    return __uint_as_float(((unsigned int)s) << 16);
}
__device__ __forceinline__ void cvt4(const float4 v, s16x4& h4, s16x4& l4) {
    const unsigned short h0 = f2bf(v.x), h1 = f2bf(v.y), h2 = f2bf(v.z), h3 = f2bf(v.w);
    h4[0] = (short)h0; h4[1] = (short)h1; h4[2] = (short)h2; h4[3] = (short)h3;
    l4[0] = (short)f2bf(v.x - bf2f(h0));
    l4[1] = (short)f2bf(v.y - bf2f(h1));
    l4[2] = (short)f2bf(v.z - bf2f(h2));
    l4[3] = (short)f2bf(v.w - bf2f(h3));
}

// ---------------------------------------------------------------------------
// e_sq[k] = np.sum(codebook[k]^2), numpy pairwise_sum semantics (verified R2)
// ---------------------------------------------------------------------------
__global__ __launch_bounds__(256) void esq_kernel(const float* __restrict__ cb,
                                                  float* __restrict__ esq) {
    int k = blockIdx.x * 256 + threadIdx.x;
    if (k >= KN) return;
    const float* row = cb + (size_t)k * DN;
    float r[8];
#pragma unroll
    for (int j = 0; j < 8; ++j) r[j] = __fmul_rn(row[j], row[j]);
#pragma unroll
    for (int i = 8; i < DN; i += 8) {
#pragma unroll
        for (int j = 0; j < 8; ++j)
            r[j] = __fadd_rn(r[j], __fmul_rn(row[i + j], row[i + j]));
    }
    esq[k] = __fadd_rn(
        __fadd_rn(__fadd_rn(r[0], r[1]), __fadd_rn(r[2], r[3])),
        __fadd_rn(__fadd_rn(r[4], r[5]), __fadd_rn(r[6], r[7])));
}

// ---------------------------------------------------------------------------
// Bit-exact d2 (reference semantics, verified R2):
//   dot: sequential __fmaf_rn chain d=0..127 ascending
//   d2 : fl(fl(zsq - fl(2*dot)) + esq)
// z read from swizzled fp32 LDS tile, cb row from global (L2-resident).
// ---------------------------------------------------------------------------
__device__ __forceinline__ float exact_d2(const float* zt, const float* __restrict__ cb,
                                          const int r, const int k,
                                          const float zsq, const float ek) {
    const float* crow = cb + (size_t)k * DN;
    float dot = 0.0f;
#pragma unroll
    for (int j = 0; j < 32; ++j) {
        const int pj = (j & ~7) | ((j ^ (r & 7)) & 7);
        const float4 zv = *reinterpret_cast<const float4*>(&zt[(r * 32 + pj) * 4]);
        const float4 cv = *reinterpret_cast<const float4*>(crow + j * 4);
        dot = __fmaf_rn(zv.x, cv.x, dot);
        dot = __fmaf_rn(zv.y, cv.y, dot);
        dot = __fmaf_rn(zv.z, cv.z, dot);
        dot = __fmaf_rn(zv.w, cv.w, dot);
    }
    return __fadd_rn(__fsub_rn(zsq, __fmul_rn(2.0f, dot)), ek);
}

// ---------------------------------------------------------------------------
// Main VQ kernel, MFMA edition. Block = 256 threads = 4 waves; 128 rows/block.
// Approx scores via split-bf16 mfma_f32_16x16x32_bf16 (zh*ch + zh*cl + zl*ch),
// per-row top-3 tracking, tiered exact rescue for correctness (see header).
// ---------------------------------------------------------------------------
__global__ __launch_bounds__(256, 1) void vq_kernel(const float* __restrict__ z,
                                                    const float* __restrict__ cb,
                                                    const float* __restrict__ esq,
                                                    float* __restrict__ out,
                                                    double* __restrict__ partials) {
    __shared__ __align__(16) float zt[ROWS * DN];            // 64 KB fp32 z (swizzled)
    __shared__ __align__(16) short cbh[2][GCODES * DN];      // 32 KB bf16 hi (dbuf, swz)
    __shared__ __align__(16) short cbl[2][GCODES * DN];      // 32 KB bf16 lo (dbuf, swz)
    __shared__ __align__(16) float sEsq[KN];                 // 4 KB
    __shared__ float  szsq[ROWS];
    __shared__ float  sB1[ROWS], sB2[ROWS], sB3[ROWS];
    __shared__ int    sI1[ROWS], sI2[ROWS];
    __shared__ int    sbidx[ROWS];
    __shared__ int    t2list[ROWS], t3list[ROWS];
    __shared__ int    t2n, t3n;
    __shared__ double sls[256];

    const int tid  = threadIdx.x;
    const int lane = tid & 63;
    const int w    = tid >> 6;
    const int l15  = lane & 15;
    const int l4h  = lane >> 4;      // 0..3
    const int row0 = blockIdx.x * ROWS;

    if (tid == 0) { t2n = 0; t3n = 0; }

    // ---- stage z: 128 rows x 512B, coalesced reads, swizzled ds writes -----
#pragma unroll
    for (int i = 0; i < 16; ++i) {
        const int g = i * 256 + tid;
        const int r = g >> 5;
        const int j = g & 31;
        const float4 v = *reinterpret_cast<const float4*>(
            z + ((size_t)(row0 + r)) * DN + j * 4);
        const int pj = (j & ~7) | ((j ^ r) & 7);
        *reinterpret_cast<float4*>(&zt[(r * 32 + pj) * 4]) = v;
    }
    // ---- stage cb group 0 -> bf16 hi/lo, swizzled 16B chunks ---------------
#pragma unroll
    for (int i = 0; i < 8; ++i) {
        const int g2 = i * 256 + tid;
        const int c  = g2 >> 5;
        const int j  = g2 & 31;
        const float4 v = *reinterpret_cast<const float4*>(
            cb + ((size_t)c) * DN + j * 4);
        s16x4 h4, l4; cvt4(v, h4, l4);
        const int off = c * DN + (((j >> 1) ^ (c & 7)) * 8) + ((j & 1) * 4);
        *reinterpret_cast<s16x4*>(&cbh[0][off]) = h4;
        *reinterpret_cast<s16x4*>(&cbl[0][off]) = l4;
    }
    // ---- stage esq ----------------------------------------------------------
#pragma unroll
    for (int i = 0; i < 4; ++i) sEsq[i * 256 + tid] = esq[i * 256 + tid];
    __syncthreads();

    // ---- zsq per row (numpy pairwise 8-acc stride-8), threads 0..127 -------
    if (tid < ROWS) {
        const int zb = tid * DN;
        const int sw = tid & 7;
        float rr[8];
#pragma unroll
        for (int c = 0; c < 32; ++c) {
            const int pj = (c & ~7) | ((c ^ sw) & 7);
            const float4 v = *reinterpret_cast<const float4*>(&zt[zb + pj * 4]);
            const int t0 = 4 * (c & 1);
            if (c < 2) {
                rr[t0 + 0] = __fmul_rn(v.x, v.x);
                rr[t0 + 1] = __fmul_rn(v.y, v.y);
                rr[t0 + 2] = __fmul_rn(v.z, v.z);
                rr[t0 + 3] = __fmul_rn(v.w, v.w);
            } else {
                rr[t0 + 0] = __fadd_rn(rr[t0 + 0], __fmul_rn(v.x, v.x));
                rr[t0 + 1] = __fadd_rn(rr[t0 + 1], __fmul_rn(v.y, v.y));
                rr[t0 + 2] = __fadd_rn(rr[t0 + 2], __fmul_rn(v.z, v.z));
                rr[t0 + 3] = __fadd_rn(rr[t0 + 3], __fmul_rn(v.w, v.w));
            }
        }
        szsq[tid] = __fadd_rn(
            __fadd_rn(__fadd_rn(rr[0], rr[1]), __fadd_rn(rr[2], rr[3])),
            __fadd_rn(__fadd_rn(rr[4], rr[5]), __fadd_rn(rr[6], rr[7])));
    }

    // ---- per-wave A fragments: 32 rows (2 tiles of 16), split bf16 ---------
    // A layout (16x16x32): lane -> row = lane&15, k = (lane>>4)*8 + e
    s16x8 zha[2][4], zla[2][4];
#pragma unroll
    for (int rt = 0; rt < 2; ++rt) {
#pragma unroll
        for (int ks = 0; ks < 4; ++ks) {
            const int rl = 32 * w + 16 * rt + l15;
            const int j0 = ks * 8 + l4h * 2;
            const int j1 = j0 + 1;
            const int pj0 = (j0 & ~7) | ((j0 ^ rl) & 7);
            const int pj1 = (j1 & ~7) | ((j1 ^ rl) & 7);
            const float4 v0 = *reinterpret_cast<const float4*>(&zt[(rl * 32 + pj0) * 4]);
            const float4 v1 = *reinterpret_cast<const float4*>(&zt[(rl * 32 + pj1) * 4]);
            s16x8 hv, lv;
            unsigned short hs; float f;
            f = v0.x; hs = f2bf(f); hv[0] = (short)hs; lv[0] = (short)f2bf(f - bf2f(hs));
            f = v0.y; hs = f2bf(f); hv[1] = (short)hs; lv[1] = (short)f2bf(f - bf2f(hs));
            f = v0.z; hs = f2bf(f); hv[2] = (short)hs; lv[2] = (short)f2bf(f - bf2f(hs));
            f = v0.w; hs = f2bf(f); hv[3] = (short)hs; lv[3] = (short)f2bf(f - bf2f(hs));
            f = v1.x; hs = f2bf(f); hv[4] = (short)hs; lv[4] = (short)f2bf(f - bf2f(hs));
            f = v1.y; hs = f2bf(f); hv[5] = (short)hs; lv[5] = (short)f2bf(f - bf2f(hs));
            f = v1.z; hs = f2bf(f); hv[6] = (short)hs; lv[6] = (short)f2bf(f - bf2f(hs));
            f = v1.w; hs = f2bf(f); hv[7] = (short)hs; lv[7] = (short)f2bf(f - bf2f(hs));
            zha[rt][ks] = hv; zla[rt][ks] = lv;
        }
    }

    // ---- per-slot top-3 state (slot = rt*4+e -> row (lane>>4)*4+e + 16rt) --
    float b1v[8], b2v[8], b3v[8]; int i1v[8], i2v[8];
#pragma unroll
    for (int s = 0; s < 8; ++s) {
        b1v[s] = INFINITY; b2v[s] = INFINITY; b3v[s] = INFINITY;
        i1v[s] = 0; i2v[s] = 0;
    }

#define UPD(s, sc, kk) { \
    const bool lt1 = (sc) < b1v[s]; \
    const bool lt2 = (sc) < b2v[s]; \
    const bool lt3 = (sc) < b3v[s]; \
    b3v[s] = lt2 ? b2v[s] : (lt3 ? (sc) : b3v[s]); \
    b2v[s] = lt1 ? b1v[s] : (lt2 ? (sc) : b2v[s]); \
    i2v[s] = lt1 ? i1v[s] : (lt2 ? (kk) : i2v[s]); \
    b1v[s] = lt1 ? (sc) : b1v[s]; \
    i1v[s] = lt1 ? (kk) : i1v[s]; }

    // ---- main loop over 16 code groups (double-buffered bf16 staging) ------
    for (int g = 0; g < NGRP; ++g) {
        const int buf = g & 1;
        const short* curh = &cbh[buf][0];
        const short* curl = &cbl[buf][0];

        // prefetch next group's cb (fp32) into registers, issue before MFMA
        float4 st0, st1, st2, st3, st4, st5, st6, st7;
        if (g < NGRP - 1) {
            const size_t gb = (size_t)(g + 1) * GCODES;
#define LDST(i, dst) { const int g2 = i * 256 + tid; \
            dst = *reinterpret_cast<const float4*>( \
                cb + (gb + (g2 >> 5)) * DN + (g2 & 31) * 4); }
            LDST(0, st0) LDST(1, st1) LDST(2, st2) LDST(3, st3)
            LDST(4, st4) LDST(5, st5) LDST(6, st6) LDST(7, st7)
#undef LDST
        }

        f32x4 acc[2][4];
#pragma unroll
        for (int rt = 0; rt < 2; ++rt)
#pragma unroll
            for (int ct = 0; ct < 4; ++ct)
                acc[rt][ct] = (f32x4){0.0f, 0.0f, 0.0f, 0.0f};

        // B layout (16x16x32): lane -> col(code) = lane&15, k = (lane>>4)*8+e
#pragma unroll
        for (int ks = 0; ks < 4; ++ks) {
#pragma unroll
            for (int ct = 0; ct < 4; ++ct) {
                const int cl_ = ct * 16 + l15;               // code in group
                const int m   = ks * 4 + l4h;                // 8-bf16 chunk
                const int pm  = m ^ (cl_ & 7);               // XOR swizzle
                const int off = cl_ * DN + pm * 8;
                const s16x8 bh = *reinterpret_cast<const s16x8*>(&curh[off]);
                const s16x8 bl = *reinterpret_cast<const s16x8*>(&curl[off]);
                acc[0][ct] = __builtin_amdgcn_mfma_f32_16x16x32_bf16(zha[0][ks], bh, acc[0][ct], 0, 0, 0);
                acc[1][ct] = __builtin_amdgcn_mfma_f32_16x16x32_bf16(zha[1][ks], bh, acc[1][ct], 0, 0, 0);
                acc[0][ct] = __builtin_amdgcn_mfma_f32_16x16x32_bf16(zla[0][ks], bh, acc[0][ct], 0, 0, 0);
                acc[1][ct] = __builtin_amdgcn_mfma_f32_16x16x32_bf16(zla[1][ks], bh, acc[1][ct], 0, 0, 0);
                acc[0][ct] = __builtin_amdgcn_mfma_f32_16x16x32_bf16(zha[0][ks], bl, acc[0][ct], 0, 0, 0);
                acc[1][ct] = __builtin_amdgcn_mfma_f32_16x16x32_bf16(zha[1][ks], bl, acc[1][ct], 0, 0, 0);
            }
        }

        // FIN: score = esq - 2*dot; per-slot top-3 update (codes ascend in k)
#pragma unroll
        for (int ct = 0; ct < 4; ++ct) {
            const int k = g * GCODES + ct * 16 + l15;
            const float ek = sEsq[k];
#pragma unroll
            for (int rt = 0; rt < 2; ++rt) {
#pragma unroll
                for (int e = 0; e < 4; ++e) {
                    const float sc = __fmaf_rn(-2.0f, acc[rt][ct][e], ek);
                    UPD(rt * 4 + e, sc, k)
                }
            }
        }

        // convert + write staged next group (race-free: barrier below)
        if (g < NGRP - 1) {
            short* nxth = &cbh[buf ^ 1][0];
            short* nxtl = &cbl[buf ^ 1][0];
#define STST(i, src) { const int g2 = i * 256 + tid; const int c = g2 >> 5; const int j = g2 & 31; \
            s16x4 h4, l4; cvt4(src, h4, l4); \
            const int off = c * DN + (((j >> 1) ^ (c & 7)) * 8) + ((j & 1) * 4); \
            *reinterpret_cast<s16x4*>(&nxth[off]) = h4; \
            *reinterpret_cast<s16x4*>(&nxtl[off]) = l4; }
            STST(0, st0) STST(1, st1) STST(2, st2) STST(3, st3)
            STST(4, st4) STST(5, st5) STST(6, st6) STST(7, st7)
#undef STST
        }
        __syncthreads();
    }
#undef UPD

    // ---- cross-lane merge: 16 lanes (same lane>>4) partition codes ----------
#pragma unroll
    for (int st = 1; st < 16; st <<= 1) {
#pragma unroll
        for (int s = 0; s < 8; ++s) {
            const float ob1 = __shfl_xor(b1v[s], st);
            const int   oi1 = __shfl_xor(i1v[s], st);
            const float ob2 = __shfl_xor(b2v[s], st);
            const int   oi2 = __shfl_xor(i2v[s], st);
            const float ob3 = __shfl_xor(b3v[s], st);
            float v1, v2, v3; int j1, j2;
            if (ob1 < b1v[s]) {
                v1 = ob1; j1 = oi1;
                if (b1v[s] < ob2) { v2 = b1v[s]; j2 = i1v[s]; v3 = fminf(b2v[s], ob2); }
                else              { v2 = ob2;    j2 = oi2;    v3 = fminf(b1v[s], ob3); }
            } else {
                v1 = b1v[s]; j1 = i1v[s];
                if (ob1 < b2v[s]) { v2 = ob1;    j2 = oi1;    v3 = fminf(ob2, b2v[s]); }
                else              { v2 = b2v[s]; j2 = i2v[s]; v3 = fminf(ob1, b3v[s]); }
            }
            b1v[s] = v1; i1v[s] = j1; b2v[s] = v2; i2v[s] = j2; b3v[s] = v3;
        }
    }
    if (l15 == 0) {
#pragma unroll
        for (int s = 0; s < 8; ++s) {
            const int r = 32 * w + 16 * (s >> 2) + l4h * 4 + (s & 3);
            sB1[r] = b1v[s]; sI1[r] = i1v[s];
            sB2[r] = b2v[s]; sI2[r] = i2v[s];
            sB3[r] = b3v[s];
        }
    }
    __syncthreads();

    // ---- classification + canary (threads 0..127, one row each) ------------
    if (tid < ROWS) {
        const float bb1 = sB1[tid];
        const int   idx = sI1[tid];
        sbidx[tid] = idx;
        // canary: winner's approx d2 vs exact d2 — gross mismatch => tier3
        const float d2x  = exact_d2(zt, cb, tid, idx, szsq[tid], sEsq[idx]);
        const float pred = __fadd_rn(szsq[tid], bb1);
        const bool bad   = fabsf(pred - d2x) > CANARY;
        if (bad || (sB3[tid] - bb1 <= TAMB)) {
            const int p = atomicAdd(&t3n, 1); t3list[p] = tid;
        } else if (sB2[tid] - bb1 <= TAMB) {
            const int p = atomicAdd(&t2n, 1); t2list[p] = tid;
        }
    }
    __syncthreads();

    // ---- tier 2: exact rescore of {i1, i2}, one thread per row -------------
    if (tid < t2n) {
        const int r  = t2list[tid];
        const int ka = sI1[r], kb = sI2[r];
        const float zsq = szsq[r];
        const float da = exact_d2(zt, cb, r, ka, zsq, sEsq[ka]);
        const float db = exact_d2(zt, cb, r, kb, zsq, sEsq[kb]);
        int win;
        if (da < db) win = ka;
        else if (db < da) win = kb;
        else win = (ka < kb) ? ka : kb;
        sbidx[r] = win;
    }
    // ---- tier 3: full exact rescan (wave-cooperative, rare) ----------------
    for (int ii = w; ii < t3n; ii += 4) {
        const int r = t3list[ii];
        const float zsq = szsq[r];
        float best = INFINITY; int bi = 0;
#pragma unroll 1
        for (int kk = 0; kk < 16; ++kk) {
            const int k = lane * 16 + kk;          // in-lane ascending k
            const float d2v = exact_d2(zt, cb, r, k, zsq, sEsq[k]);
            if (d2v < best) { best = d2v; bi = k; }
        }
#pragma unroll
        for (int m = 1; m < 64; m <<= 1) {
            const float ob  = __shfl_xor(best, m);
            const int   obi = __shfl_xor(bi, m);
            if (ob < best || (ob == best && obi < bi)) { best = ob; bi = obi; }
        }
        if (lane == 0) sbidx[r] = bi;
    }
    __syncthreads();

    // ---- indices out --------------------------------------------------------
    if (tid < ROWS)
        out[(size_t)BN * DN + 1 + row0 + tid] = (float)sbidx[tid];

    // ---- epilogue: coalesced z_q gather/write + fp64 loss ------------------
    double ls = 0.0;
#pragma unroll
    for (int it = 0; it < 16; ++it) {
        const int r  = it * 8 + (tid >> 5);
        const int j  = tid & 31;
        const int pj = (j & ~7) | ((j ^ (r & 7)) & 7);
        const float4 zv = *reinterpret_cast<const float4*>(&zt[(r * 32 + pj) * 4]);
        const int bfin = sbidx[r];
        const float4 cv = *reinterpret_cast<const float4*>(
            cb + ((size_t)bfin) * DN + j * 4);
        *reinterpret_cast<float4*>(out + ((size_t)(row0 + r)) * DN + j * 4) = cv;
        const float d0 = __fsub_rn(cv.x, zv.x);
        const float d1 = __fsub_rn(cv.y, zv.y);
        const float d2e = __fsub_rn(cv.z, zv.z);
        const float d3 = __fsub_rn(cv.w, zv.w);
        ls += (double)__fmul_rn(d0, d0);
        ls += (double)__fmul_rn(d1, d1);
        ls += (double)__fmul_rn(d2e, d2e);
        ls += (double)__fmul_rn(d3, d3);
    }
    sls[tid] = ls;
    __syncthreads();
    for (int s = 128; s > 0; s >>= 1) {
        if (tid < s) sls[tid] += sls[tid + s];
        __syncthreads();
    }
    if (tid == 0) partials[blockIdx.x] = sls[0];
}

// ---------------------------------------------------------------------------
// Final loss reduction over NBLK block partials (deterministic)
// ---------------------------------------------------------------------------
__global__ __launch_bounds__(256) void loss_kernel(const double* __restrict__ partials,
                                                   float* __restrict__ out) {
    __shared__ double s[256];
    double acc = 0.0;
    for (int i = threadIdx.x; i < NBLK; i += 256) acc += partials[i];
    s[threadIdx.x] = acc;
    __syncthreads();
    for (int t = 128; t > 0; t >>= 1) {
        if (threadIdx.x < t) s[threadIdx.x] += s[threadIdx.x + t];
        __syncthreads();
    }
    if (threadIdx.x == 0)
        out[(size_t)BN * DN] = (float)(s[0] / ((double)BN * (double)DN));
}

extern "C" void kernel_launch(void* const* d_in, const int* in_sizes, int n_in,
                              void* d_out, int out_size, void* d_ws, size_t ws_size,
                              hipStream_t stream) {
    const float* z  = (const float*)d_in[0];
    const float* cb = (const float*)d_in[1];
    float* out = (float*)d_out;

    // Workspace: [0,4096) e_sq floats; [4096, 4096+8192) NBLK double partials
    float*  esq      = (float*)d_ws;
    double* partials = (double*)((char*)d_ws + 4096);

    esq_kernel <<<KN / 256, 256, 0, stream>>>(cb, esq);
    vq_kernel  <<<NBLK, 256, 0, stream>>>(z, cb, esq, out, partials);
    loss_kernel<<<1, 256, 0, stream>>>(partials, out);
}

// Round 2
// 284.386 us; speedup vs baseline: 2.2302x; 1.2613x over previous
//
#include <hip/hip_runtime.h>
#include <math.h>

// Problem constants
#define BN 131072
#define KN 1024
#define DN 128
#define ROWS 64               // z rows per block
#define NBLK (BN / ROWS)      // 2048 blocks
#define GCODES 64             // codes per staged group
#define NGRP (KN / GCODES)    // 16 groups

// Ambiguity threshold on approx scores (esq - 2*dot).
#define TAMB 2.5e-4f
// Canary: gross mismatch (e.g. wrong MFMA layout) -> full exact rescan.
#define CANARY 0.01f

typedef __attribute__((ext_vector_type(8))) short s16x8;   // 8 bf16 (4 VGPR)
typedef __attribute__((ext_vector_type(4))) short s16x4;   // 4 bf16 (8B)
typedef __attribute__((ext_vector_type(4))) float f32x4;   // MFMA C/D

__device__ __forceinline__ unsigned short f2bf(float f) {
    const unsigned int u = __float_as_uint(f);
    return (unsigned short)((u + 0x7fffu + ((u >> 16) & 1u)) >> 16);
}
__device__ __forceinline__ float bf2f(unsigned short s) {
    return __uint_as_float(((unsigned int)s) << 16);
}
__device__ __forceinline__ void cvt4(const float4 v, s16x4& h4, s16x4& l4) {
    const unsigned short h0 = f2bf(v.x), h1 = f2bf(v.y), h2 = f2bf(v.z), h3 = f2bf(v.w);
    h4[0] = (short)h0; h4[1] = (short)h1; h4[2] = (short)h2; h4[3] = (short)h3;
    l4[0] = (short)f2bf(v.x - bf2f(h0));
    l4[1] = (short)f2bf(v.y - bf2f(h1));
    l4[2] = (short)f2bf(v.z - bf2f(h2));
    l4[3] = (short)f2bf(v.w - bf2f(h3));
}
__device__ __forceinline__ void cvt8(const float4 v0, const float4 v1,
                                     s16x8& h, s16x8& l) {
    s16x4 h0, l0, h1, l1;
    cvt4(v0, h0, l0); cvt4(v1, h1, l1);
    h[0]=h0[0]; h[1]=h0[1]; h[2]=h0[2]; h[3]=h0[3];
    h[4]=h1[0]; h[5]=h1[1]; h[6]=h1[2]; h[7]=h1[3];
    l[0]=l0[0]; l[1]=l0[1]; l[2]=l0[2]; l[3]=l0[3];
    l[4]=l1[0]; l[5]=l1[1]; l[6]=l1[2]; l[7]=l1[3];
}

// ---------------------------------------------------------------------------
// e_sq[k] = np.sum(codebook[k]^2), numpy pairwise_sum semantics (verified)
// ---------------------------------------------------------------------------
__global__ __launch_bounds__(256) void esq_kernel(const float* __restrict__ cb,
                                                  float* __restrict__ esq) {
    int k = blockIdx.x * 256 + threadIdx.x;
    if (k >= KN) return;
    const float* row = cb + (size_t)k * DN;
    float r[8];
#pragma unroll
    for (int j = 0; j < 8; ++j) r[j] = __fmul_rn(row[j], row[j]);
#pragma unroll
    for (int i = 8; i < DN; i += 8) {
#pragma unroll
        for (int j = 0; j < 8; ++j)
            r[j] = __fadd_rn(r[j], __fmul_rn(row[i + j], row[i + j]));
    }
    esq[k] = __fadd_rn(
        __fadd_rn(__fadd_rn(r[0], r[1]), __fadd_rn(r[2], r[3])),
        __fadd_rn(__fadd_rn(r[4], r[5]), __fadd_rn(r[6], r[7])));
}

// ---------------------------------------------------------------------------
// One-shot codebook conversion: fp32 cb -> bf16 hi/lo planes, fragment-linear
// chunk-major layout per 64-code group:
//   h chunk (m,c): planes[g*16384 + (m*64 + c)*8 + e]   (m = dim/8, c = code)
//   l chunk (m,c): planes[g*16384 + 8192 + (m*64+c)*8 + e]
// This makes in-kernel staging a pure linear memcpy, and B-fragment
// ds_read_b128 a 256B-contiguous (conflict-free) pattern per quarter-wave.
// ---------------------------------------------------------------------------
__global__ __launch_bounds__(256) void cvt_kernel(const float* __restrict__ cb,
                                                  unsigned short* __restrict__ pl) {
    const int t = blockIdx.x * 256 + threadIdx.x;     // 16384 threads
    const int g = t >> 10, rem = t & 1023;
    const int m = rem >> 6, c = rem & 63;
    const float* src = cb + ((size_t)(g * 64 + c)) * DN + m * 8;
    const float4 v0 = *reinterpret_cast<const float4*>(src);
    const float4 v1 = *reinterpret_cast<const float4*>(src + 4);
    s16x8 h, l;
    cvt8(v0, v1, h, l);
    unsigned short* hb = pl + (size_t)g * 16384 + (m * 64 + c) * 8;
    *reinterpret_cast<s16x8*>(hb)        = h;
    *reinterpret_cast<s16x8*>(hb + 8192) = l;
}

// ---------------------------------------------------------------------------
// Bit-exact d2 (reference semantics): sequential fma chain d=0..127 ascending;
// d2 = fl(fl(zsq - fl(2*dot)) + esq). z and cb read from global (L2-warm).
// ---------------------------------------------------------------------------
__device__ __forceinline__ float exact_d2_g(const float* __restrict__ z,
                                            const float* __restrict__ cb,
                                            const int grow, const int k,
                                            const float zsq, const float ek) {
    const float* zr = z + (size_t)grow * DN;
    const float* cr = cb + (size_t)k * DN;
    float dot = 0.0f;
#pragma unroll
    for (int j = 0; j < 32; ++j) {
        const float4 zv = *reinterpret_cast<const float4*>(zr + j * 4);
        const float4 cv = *reinterpret_cast<const float4*>(cr + j * 4);
        dot = __fmaf_rn(zv.x, cv.x, dot);
        dot = __fmaf_rn(zv.y, cv.y, dot);
        dot = __fmaf_rn(zv.z, cv.z, dot);
        dot = __fmaf_rn(zv.w, cv.w, dot);
    }
    return __fadd_rn(__fsub_rn(zsq, __fmul_rn(2.0f, dot)), ek);
}

// ---------------------------------------------------------------------------
// Main VQ kernel. 2048 blocks x 256 threads (4 waves), 64 rows/block.
// LDS ~75KB -> 2 blocks/CU (2 waves/SIMD, independent barriers).
// Wave grid 2x2: wave (wr,wc) owns rows wr*32..+31, codes wc*32..+31 of group.
// Approx scores via split-bf16 mfma_f32_16x16x32_bf16 (hi*bh, lo*bh, hi*bl —
// same order/operands as the validated R1 kernel -> bit-identical scores).
// Tiered exact rescue (top-3 + TAMB band + canary) for bit-exact argmin.
// ---------------------------------------------------------------------------
template <bool PREP>
__global__ __launch_bounds__(256, 2) void vq_kernel(const float* __restrict__ z,
                                                    const float* __restrict__ cb,
                                                    const unsigned short* __restrict__ planes,
                                                    const float* __restrict__ esq,
                                                    float* __restrict__ out,
                                                    double* __restrict__ partials) {
    __shared__ __align__(16) short cbS[2][16384];   // 64 KB: [buf][plane|m|c|e]
    __shared__ __align__(16) float sEsq[KN];        // 4 KB
    __shared__ float  szsq[ROWS];
    __shared__ float  sB1[2][ROWS], sB2[2][ROWS], sB3[2][ROWS];
    __shared__ int    sI1[2][ROWS], sI2[2][ROWS];
    __shared__ int    sbidx[ROWS];
    __shared__ int    t2list[ROWS], t3list[ROWS];
    __shared__ int    t2n, t3n;
    __shared__ double sls[256];

    const int tid  = threadIdx.x;
    const int lane = tid & 63;
    const int w    = tid >> 6;
    const int l15  = lane & 15;
    const int l4h  = lane >> 4;      // 0..3
    const int wr   = w >> 1;         // 0..1: row half
    const int wc   = w & 1;          // 0..1: code half
    const int row0 = blockIdx.x * ROWS;

    if (tid == 0) { t2n = 0; t3n = 0; }

    // ---- stage esq ---------------------------------------------------------
#pragma unroll
    for (int i = 0; i < 4; ++i) sEsq[i * 256 + tid] = esq[i * 256 + tid];

    // ---- stage group 0: issue loads early ----------------------------------
    float4 stg[8];
    if constexpr (PREP) {
#pragma unroll
        for (int i = 0; i < 8; ++i)
            stg[i] = *reinterpret_cast<const float4*>(planes + (i * 256 + tid) * 8);
    } else {
#pragma unroll
        for (int i = 0; i < 4; ++i) {
            const int mc = i * 256 + tid, m = mc >> 6, c = mc & 63;
            const float* src = cb + ((size_t)c) * DN + m * 8;
            stg[2 * i]     = *reinterpret_cast<const float4*>(src);
            stg[2 * i + 1] = *reinterpret_cast<const float4*>(src + 4);
        }
    }

    // ---- zsq per row (numpy pairwise 8-acc stride-8), threads 0..63 --------
    if (tid < ROWS) {
        const float* zr = z + (size_t)(row0 + tid) * DN;
        float rr[8];
#pragma unroll
        for (int c = 0; c < 32; ++c) {
            const float4 v = *reinterpret_cast<const float4*>(zr + c * 4);
            const int t0 = 4 * (c & 1);
            if (c < 2) {
                rr[t0 + 0] = __fmul_rn(v.x, v.x);
                rr[t0 + 1] = __fmul_rn(v.y, v.y);
                rr[t0 + 2] = __fmul_rn(v.z, v.z);
                rr[t0 + 3] = __fmul_rn(v.w, v.w);
            } else {
                rr[t0 + 0] = __fadd_rn(rr[t0 + 0], __fmul_rn(v.x, v.x));
                rr[t0 + 1] = __fadd_rn(rr[t0 + 1], __fmul_rn(v.y, v.y));
                rr[t0 + 2] = __fadd_rn(rr[t0 + 2], __fmul_rn(v.z, v.z));
                rr[t0 + 3] = __fadd_rn(rr[t0 + 3], __fmul_rn(v.w, v.w));
            }
        }
        szsq[tid] = __fadd_rn(
            __fadd_rn(__fadd_rn(rr[0], rr[1]), __fadd_rn(rr[2], rr[3])),
            __fadd_rn(__fadd_rn(rr[4], rr[5]), __fadd_rn(rr[6], rr[7])));
    }

    // ---- write staged group 0 ----------------------------------------------
    {
        short* dst = &cbS[0][0];
        if constexpr (PREP) {
#pragma unroll
            for (int i = 0; i < 8; ++i)
                *reinterpret_cast<float4*>(dst + (i * 256 + tid) * 8) = stg[i];
        } else {
#pragma unroll
            for (int i = 0; i < 4; ++i) {
                const int mc = i * 256 + tid, m = mc >> 6, c = mc & 63;
                s16x4 h0, l0, h1, l1;
                cvt4(stg[2 * i], h0, l0); cvt4(stg[2 * i + 1], h1, l1);
                short* hb = dst + (m * 64 + c) * 8;
                *reinterpret_cast<s16x4*>(hb)     = h0;
                *reinterpret_cast<s16x4*>(hb + 4) = h1;
                short* lb = hb + 8192;
                *reinterpret_cast<s16x4*>(lb)     = l0;
                *reinterpret_cast<s16x4*>(lb + 4) = l1;
            }
        }
    }

    // ---- A fragments from global z: 32 rows/wave (2 tiles), split bf16 -----
    // A layout (16x16x32): lane -> row = lane&15, k = (lane>>4)*8 + e
    s16x8 zha[2][4], zla[2][4];
#pragma unroll
    for (int rt = 0; rt < 2; ++rt) {
#pragma unroll
        for (int ks = 0; ks < 4; ++ks) {
            const int rl = row0 + wr * 32 + rt * 16 + l15;
            const float* src = z + (size_t)rl * DN + ks * 32 + l4h * 8;
            const float4 v0 = *reinterpret_cast<const float4*>(src);
            const float4 v1 = *reinterpret_cast<const float4*>(src + 4);
            cvt8(v0, v1, zha[rt][ks], zla[rt][ks]);
        }
    }
    __syncthreads();

    // ---- per-slot top-3 state (slot = rt*4+e -> row wr*32+rt*16+l4h*4+e) ---
    float b1v[8], b2v[8], b3v[8]; int i1v[8], i2v[8];
#pragma unroll
    for (int s = 0; s < 8; ++s) {
        b1v[s] = INFINITY; b2v[s] = INFINITY; b3v[s] = INFINITY;
        i1v[s] = 0; i2v[s] = 0;
    }

#define UPD(s, sc, kk) { \
    const bool lt1 = (sc) < b1v[s]; \
    const bool lt2 = (sc) < b2v[s]; \
    const bool lt3 = (sc) < b3v[s]; \
    b3v[s] = lt2 ? b2v[s] : (lt3 ? (sc) : b3v[s]); \
    b2v[s] = lt1 ? b1v[s] : (lt2 ? (sc) : b2v[s]); \
    i2v[s] = lt1 ? i1v[s] : (lt2 ? (kk) : i2v[s]); \
    b1v[s] = lt1 ? (sc) : b1v[s]; \
    i1v[s] = lt1 ? (kk) : i1v[s]; }

    // ---- main loop over 16 code groups -------------------------------------
    for (int g = 0; g < NGRP; ++g) {
        const int buf = g & 1;

        // prefetch next group's staged data (issue before MFMA)
        if (g < NGRP - 1) {
            if constexpr (PREP) {
                const unsigned short* srcg = planes + (size_t)(g + 1) * 16384;
#pragma unroll
                for (int i = 0; i < 8; ++i)
                    stg[i] = *reinterpret_cast<const float4*>(srcg + (i * 256 + tid) * 8);
            } else {
                const int gb = (g + 1) * GCODES;
#pragma unroll
                for (int i = 0; i < 4; ++i) {
                    const int mc = i * 256 + tid, m = mc >> 6, c = mc & 63;
                    const float* src = cb + ((size_t)(gb + c)) * DN + m * 8;
                    stg[2 * i]     = *reinterpret_cast<const float4*>(src);
                    stg[2 * i + 1] = *reinterpret_cast<const float4*>(src + 4);
                }
            }
        }

        f32x4 acc[2][2];
#pragma unroll
        for (int rt = 0; rt < 2; ++rt)
#pragma unroll
            for (int ct = 0; ct < 2; ++ct)
                acc[rt][ct] = (f32x4){0.0f, 0.0f, 0.0f, 0.0f};

        // B layout (16x16x32): lane -> col(code)=lane&15, k=(lane>>4)*8+e.
        // Chunk-major LDS: 16B chunk index = m*64 + code; quarter-wave reads
        // 256B contiguous -> conflict-free.
#pragma unroll
        for (int ks = 0; ks < 4; ++ks) {
            const int b0 = (((ks * 4 + l4h) << 6) + (wc << 5) + l15) << 3;  // shorts
            const s16x8 bh0 = *reinterpret_cast<const s16x8*>(&cbS[buf][b0]);
            const s16x8 bl0 = *reinterpret_cast<const s16x8*>(&cbS[buf][8192 + b0]);
            const s16x8 bh1 = *reinterpret_cast<const s16x8*>(&cbS[buf][b0 + 128]);
            const s16x8 bl1 = *reinterpret_cast<const s16x8*>(&cbS[buf][8192 + b0 + 128]);
            acc[0][0] = __builtin_amdgcn_mfma_f32_16x16x32_bf16(zha[0][ks], bh0, acc[0][0], 0, 0, 0);
            acc[0][0] = __builtin_amdgcn_mfma_f32_16x16x32_bf16(zla[0][ks], bh0, acc[0][0], 0, 0, 0);
            acc[0][0] = __builtin_amdgcn_mfma_f32_16x16x32_bf16(zha[0][ks], bl0, acc[0][0], 0, 0, 0);
            acc[1][0] = __builtin_amdgcn_mfma_f32_16x16x32_bf16(zha[1][ks], bh0, acc[1][0], 0, 0, 0);
            acc[1][0] = __builtin_amdgcn_mfma_f32_16x16x32_bf16(zla[1][ks], bh0, acc[1][0], 0, 0, 0);
            acc[1][0] = __builtin_amdgcn_mfma_f32_16x16x32_bf16(zha[1][ks], bl0, acc[1][0], 0, 0, 0);
            acc[0][1] = __builtin_amdgcn_mfma_f32_16x16x32_bf16(zha[0][ks], bh1, acc[0][1], 0, 0, 0);
            acc[0][1] = __builtin_amdgcn_mfma_f32_16x16x32_bf16(zla[0][ks], bh1, acc[0][1], 0, 0, 0);
            acc[0][1] = __builtin_amdgcn_mfma_f32_16x16x32_bf16(zha[0][ks], bl1, acc[0][1], 0, 0, 0);
            acc[1][1] = __builtin_amdgcn_mfma_f32_16x16x32_bf16(zha[1][ks], bh1, acc[1][1], 0, 0, 0);
            acc[1][1] = __builtin_amdgcn_mfma_f32_16x16x32_bf16(zla[1][ks], bh1, acc[1][1], 0, 0, 0);
            acc[1][1] = __builtin_amdgcn_mfma_f32_16x16x32_bf16(zha[1][ks], bl1, acc[1][1], 0, 0, 0);
        }

        // FIN: score = esq - 2*dot; top-3 update (candidates ascend in k)
#pragma unroll
        for (int ct = 0; ct < 2; ++ct) {
            const int k = g * GCODES + wc * 32 + ct * 16 + l15;
            const float ek = sEsq[k];
#pragma unroll
            for (int rt = 0; rt < 2; ++rt) {
#pragma unroll
                for (int e = 0; e < 4; ++e) {
                    const float sc = __fmaf_rn(-2.0f, acc[rt][ct][e], ek);
                    UPD(rt * 4 + e, sc, k)
                }
            }
        }

        // write staged next group (other buffer; race-free: barrier below)
        if (g < NGRP - 1) {
            short* dst = &cbS[buf ^ 1][0];
            if constexpr (PREP) {
#pragma unroll
                for (int i = 0; i < 8; ++i)
                    *reinterpret_cast<float4*>(dst + (i * 256 + tid) * 8) = stg[i];
            } else {
#pragma unroll
                for (int i = 0; i < 4; ++i) {
                    const int mc = i * 256 + tid, m = mc >> 6, c = mc & 63;
                    s16x4 h0, l0, h1, l1;
                    cvt4(stg[2 * i], h0, l0); cvt4(stg[2 * i + 1], h1, l1);
                    short* hb = dst + (m * 64 + c) * 8;
                    *reinterpret_cast<s16x4*>(hb)     = h0;
                    *reinterpret_cast<s16x4*>(hb + 4) = h1;
                    short* lb = hb + 8192;
                    *reinterpret_cast<s16x4*>(lb)     = l0;
                    *reinterpret_cast<s16x4*>(lb + 4) = l1;
                }
            }
        }
        __syncthreads();
    }
#undef UPD

    // ---- cross-lane merge: 16 lanes (same l4h) partition codes -------------
#pragma unroll
    for (int st = 1; st < 16; st <<= 1) {
#pragma unroll
        for (int s = 0; s < 8; ++s) {
            const float ob1 = __shfl_xor(b1v[s], st);
            const int   oi1 = __shfl_xor(i1v[s], st);
            const float ob2 = __shfl_xor(b2v[s], st);
            const int   oi2 = __shfl_xor(i2v[s], st);
            const float ob3 = __shfl_xor(b3v[s], st);
            float v1, v2, v3; int j1, j2;
            if (ob1 < b1v[s]) {
                v1 = ob1; j1 = oi1;
                if (b1v[s] < ob2) { v2 = b1v[s]; j2 = i1v[s]; v3 = fminf(b2v[s], ob2); }
                else              { v2 = ob2;    j2 = oi2;    v3 = fminf(b1v[s], ob3); }
            } else {
                v1 = b1v[s]; j1 = i1v[s];
                if (ob1 < b2v[s]) { v2 = ob1;    j2 = oi1;    v3 = fminf(ob2, b2v[s]); }
                else              { v2 = b2v[s]; j2 = i2v[s]; v3 = fminf(ob1, b3v[s]); }
            }
            b1v[s] = v1; i1v[s] = j1; b2v[s] = v2; i2v[s] = j2; b3v[s] = v3;
        }
    }
    if (l15 == 0) {
#pragma unroll
        for (int s = 0; s < 8; ++s) {
            const int r = wr * 32 + (s >> 2) * 16 + l4h * 4 + (s & 3);
            sB1[wc][r] = b1v[s]; sI1[wc][r] = i1v[s];
            sB2[wc][r] = b2v[s]; sI2[wc][r] = i2v[s];
            sB3[wc][r] = b3v[s];
        }
    }
    __syncthreads();

    // ---- classification + canary (threads 0..63, one row each) -------------
    if (tid < ROWS) {
        const float a1 = sB1[0][tid]; const int aj1 = sI1[0][tid];
        const float a2 = sB2[0][tid]; const int aj2 = sI2[0][tid];
        const float a3 = sB3[0][tid];
        const float c1 = sB1[1][tid]; const int cj1 = sI1[1][tid];
        const float c2 = sB2[1][tid]; const int cj2 = sI2[1][tid];
        const float c3 = sB3[1][tid];
        float b1, b2, b3; int i1, i2;
        if (a1 <= c1) {
            b1 = a1; i1 = aj1;
            if (a2 <= c1) { b2 = a2; i2 = aj2; b3 = fminf(a3, c1); }
            else          { b2 = c1; i2 = cj1; b3 = fminf(a2, c2); }
        } else {
            b1 = c1; i1 = cj1;
            if (c2 <= a1) { b2 = c2; i2 = cj2; b3 = fminf(c3, a1); }
            else          { b2 = a1; i2 = aj1; b3 = fminf(c2, a2); }
        }
        sbidx[tid] = i1;
        sI1[0][tid] = i1; sI2[0][tid] = i2;   // for tier-2 readers
        const float d2x  = exact_d2_g(z, cb, row0 + tid, i1, szsq[tid], sEsq[i1]);
        const float pred = __fadd_rn(szsq[tid], b1);
        const bool bad   = fabsf(pred - d2x) > CANARY;
        if (bad || (b3 - b1 <= TAMB)) {
            const int p = atomicAdd(&t3n, 1); t3list[p] = tid;
        } else if (b2 - b1 <= TAMB) {
            const int p = atomicAdd(&t2n, 1); t2list[p] = tid;
        }
    }
    __syncthreads();

    // ---- tier 2: exact rescore of {i1, i2}, one thread per row -------------
    if (tid < t2n) {
        const int r  = t2list[tid];
        const int ka = sI1[0][r], kb = sI2[0][r];
        const float zsq = szsq[r];
        const float da = exact_d2_g(z, cb, row0 + r, ka, zsq, sEsq[ka]);
        const float db = exact_d2_g(z, cb, row0 + r, kb, zsq, sEsq[kb]);
        int win;
        if (da < db) win = ka;
        else if (db < da) win = kb;
        else win = (ka < kb) ? ka : kb;
        sbidx[r] = win;
    }
    // ---- tier 3: full exact rescan (wave-cooperative, rare) ----------------
    for (int ii = w; ii < t3n; ii += 4) {
        const int r = t3list[ii];
        const float zsq = szsq[r];
        float best = INFINITY; int bi = 0;
#pragma unroll 1
        for (int kk = 0; kk < 16; ++kk) {
            const int k = lane * 16 + kk;          // in-lane ascending k
            const float d2v = exact_d2_g(z, cb, row0 + r, k, zsq, sEsq[k]);
            if (d2v < best) { best = d2v; bi = k; }
        }
#pragma unroll
        for (int m = 1; m < 64; m <<= 1) {
            const float ob  = __shfl_xor(best, m);
            const int   obi = __shfl_xor(bi, m);
            if (ob < best || (ob == best && obi < bi)) { best = ob; bi = obi; }
        }
        if (lane == 0) sbidx[r] = bi;
    }
    __syncthreads();

    // ---- indices out --------------------------------------------------------
    if (tid < ROWS)
        out[(size_t)BN * DN + 1 + row0 + tid] = (float)sbidx[tid];

    // ---- epilogue: coalesced z_q gather/write + fp64 loss ------------------
    double ls = 0.0;
#pragma unroll
    for (int it = 0; it < 8; ++it) {
        const int r = it * 8 + (tid >> 5);
        const int j = tid & 31;
        const float4 zv = *reinterpret_cast<const float4*>(
            z + ((size_t)(row0 + r)) * DN + j * 4);
        const int bfin = sbidx[r];
        const float4 cv = *reinterpret_cast<const float4*>(
            cb + ((size_t)bfin) * DN + j * 4);
        *reinterpret_cast<float4*>(out + ((size_t)(row0 + r)) * DN + j * 4) = cv;
        const float d0 = __fsub_rn(cv.x, zv.x);
        const float d1 = __fsub_rn(cv.y, zv.y);
        const float d2e = __fsub_rn(cv.z, zv.z);
        const float d3 = __fsub_rn(cv.w, zv.w);
        ls += (double)__fmul_rn(d0, d0);
        ls += (double)__fmul_rn(d1, d1);
        ls += (double)__fmul_rn(d2e, d2e);
        ls += (double)__fmul_rn(d3, d3);
    }
    sls[tid] = ls;
    __syncthreads();
    for (int s = 128; s > 0; s >>= 1) {
        if (tid < s) sls[tid] += sls[tid + s];
        __syncthreads();
    }
    if (tid == 0) partials[blockIdx.x] = sls[0];
}

// ---------------------------------------------------------------------------
// Final loss reduction over NBLK block partials (deterministic)
// ---------------------------------------------------------------------------
__global__ __launch_bounds__(256) void loss_kernel(const double* __restrict__ partials,
                                                   float* __restrict__ out) {
    __shared__ double s[256];
    double acc = 0.0;
    for (int i = threadIdx.x; i < NBLK; i += 256) acc += partials[i];
    s[threadIdx.x] = acc;
    __syncthreads();
    for (int t = 128; t > 0; t >>= 1) {
        if (threadIdx.x < t) s[threadIdx.x] += s[threadIdx.x + t];
        __syncthreads();
    }
    if (threadIdx.x == 0)
        out[(size_t)BN * DN] = (float)(s[0] / ((double)BN * (double)DN));
}

extern "C" void kernel_launch(void* const* d_in, const int* in_sizes, int n_in,
                              void* d_out, int out_size, void* d_ws, size_t ws_size,
                              hipStream_t stream) {
    const float* z  = (const float*)d_in[0];
    const float* cb = (const float*)d_in[1];
    float* out = (float*)d_out;

    // Workspace: [0,4K) esq; [4K, 20K) NBLK double partials; [20K, 532K) planes
    float*          esq      = (float*)d_ws;
    double*         partials = (double*)((char*)d_ws + 4096);
    unsigned short* planes   = (unsigned short*)((char*)d_ws + 4096 + 16384);
    const size_t need = 4096 + 16384 + (size_t)KN * DN * 2 * 2;  // 544768 B

    esq_kernel<<<KN / 256, 256, 0, stream>>>(cb, esq);
    if (ws_size >= need) {
        cvt_kernel<<<64, 256, 0, stream>>>(cb, planes);
        vq_kernel<true><<<NBLK, 256, 0, stream>>>(z, cb, planes, esq, out, partials);
    } else {
        vq_kernel<false><<<NBLK, 256, 0, stream>>>(z, cb, planes, esq, out, partials);
    }
    loss_kernel<<<1, 256, 0, stream>>>(partials, out);
}